// Round 11
// baseline (210.154 us; speedup 1.0000x reference)
//
#include <hip/hip_runtime.h>

// GraphConvLayer on MI355X (gfx950). f32 I/O, bf16 inside MFMA.
// softmax_j(src_i+dst_j+b) over neighbors == e_j/sum(e)  (src_i, b cancel).
// SINGLE kernel, per-group dependency barriers (no global barrier):
//   Block (bp,it) [416 = 32 groups x 13]:
//     Phase A: its 2 sub-blocks build b1t tiles (b=2bp+sub, jt=it) ->
//              Bt[n][k]: n=b*64+f -> bf16(e_bj*X[b,j,f]); n=4096+b -> bf16(e_bj)
//     group barrier (13 blocks, counter in ws, device-scope fences)
//     Phase B: acc = A_it @ Bt_panel^T (K=832, dbuf; A converted INLINE from adj
//              via int4->regs->swizzled ds_write, T14 issue-early/write-late);
//              den via extra B-frag (garbage cols >= pad provably unused);
//              AB2=[bf16(X)|bf16(acc/den)]; W2 reg-staged from Ws/Wn;
//              out = relu(LN(AB2@W2^T + bias))

typedef unsigned short u16;
typedef unsigned int u32;
typedef short bf16x8 __attribute__((ext_vector_type(8)));
typedef float f32x4 __attribute__((ext_vector_type(4)));

#define NNODE 784
#define MP 832      // K of big GEMM (padded node count)
#define BUFU 13312  // u16 per dbuf: A 64x64 (4096) + B 144x64 (9216)

__device__ __forceinline__ float b2f(u16 h) {
  union { u32 u; float f; } v; v.u = ((u32)h) << 16; return v.f;
}
__device__ __forceinline__ u16 f2b(float f) {
  union { float f; u32 u; } v; v.f = f;
  u32 r = (v.u + 0x7FFFu + ((v.u >> 16) & 1u)) >> 16;
  return (u16)r;
}
__device__ __forceinline__ void gload16(const u16* g, u16* l) {
  __builtin_amdgcn_global_load_lds((const __attribute__((address_space(1))) u32*)g,
                                   (__attribute__((address_space(3))) u32*)l, 16, 0, 0);
}

__global__ __launch_bounds__(512, 4) void k_all(const int* __restrict__ adj,
                                                const float* __restrict__ Ws,
                                                const float* __restrict__ Wn,
                                                const float* __restrict__ X,
                                                const float* __restrict__ adst,
                                                const float* __restrict__ bs,
                                                const float* __restrict__ bn,
                                                const float* __restrict__ gam,
                                                const float* __restrict__ bet,
                                                u16* __restrict__ Bt,
                                                u32* __restrict__ cnt,
                                                float* __restrict__ out) {
  __shared__ __align__(16) u16 lds[2 * BUFU];   // phase A overlay / dbuf / epilogue
  __shared__ float denL[64][2];
  __shared__ float bsL[64], bnL[64], gamL[64], betL[64];
  const int bid = blockIdx.x;
  const int t = threadIdx.x;
  const int l = t & 63, w = t >> 6;             // 8 waves
  const int g = l >> 4, l15 = l & 15;
  const int wr = w >> 2, wc = w & 3;

  const int wg = (bid & 7) * 52 + (bid >> 3);   // 416 = 8*52 bijective XCD swizzle
  const int bp = wg / 13;                       // group = batch pair 0..31 (XCD-local)
  const int it = wg - bp * 13;                  // node tile 0..12
  const int i0 = it * 64;
  const int nb0 = bp * 128;                     // Bt feat rows
  const int nd0 = 4096 + 2 * bp;                // Bt denom rows

  // ================= Phase A: this block's 2 b1t tiles (sub-blocks concurrent) ====
  {
    const int sub = t >> 8, t256 = t & 255;
    float* Xs = (float*)((char*)lds + sub * 17920);   // [64][68] f32
    float* ad = Xs + 64 * 68;                          // [64]
    float* es = ad + 64;                               // [64]
    const int b = 2 * bp + sub;
    const int j0 = it * 64;
    const int jr = t256 >> 2, cg = t256 & 3;
    {
      int j = j0 + jr;
      float4 z4; z4.x = 0.f; z4.y = 0.f; z4.z = 0.f; z4.w = 0.f;
      float4 v0 = z4, v1 = z4, v2 = z4, v3 = z4;
      if (j < NNODE) {
        const float4* xp = (const float4*)(X + ((size_t)b * NNODE + j) * 64 + cg * 16);
        v0 = xp[0]; v1 = xp[1]; v2 = xp[2]; v3 = xp[3];
      }
      float4* d = (float4*)&Xs[jr * 68 + cg * 16];
      d[0] = v0; d[1] = v1; d[2] = v2; d[3] = v3;
      if (t256 < 64) ad[t256] = adst[t256];
    }
    __syncthreads();
    {
      float dot = 0.f;
#pragma unroll
      for (int q = 0; q < 16; ++q) dot += Xs[jr * 68 + cg * 16 + q] * ad[cg * 16 + q];
      dot += __shfl_xor(dot, 1);
      dot += __shfl_xor(dot, 2);
      if (cg == 0) es[jr] = (j0 + jr < NNODE) ? __expf(dot) : 0.f;
    }
    __syncthreads();
    {
      int f = t256 >> 2, jc = (t256 & 3) * 16;
      __align__(16) u16 ob[16];
#pragma unroll
      for (int q = 0; q < 16; ++q) ob[q] = f2b(es[jc + q] * Xs[(jc + q) * 68 + f]);
      u16* op = Bt + ((size_t)b * 64 + f) * MP + j0 + jc;
      *(uint4*)op = *(const uint4*)ob;
      *(uint4*)(op + 8) = *(const uint4*)(ob + 8);
      if (t256 < 64) Bt[(size_t)(4096 + b) * MP + j0 + t256] = f2b(es[t256]);
    }
  }
  // ---- group barrier: wait for the 12 peer blocks producing this Bt panel
  __threadfence();                              // release Bt writes (device scope)
  __syncthreads();
  if (t == 0) {
    atomicAdd(&cnt[bp], 1u);
    while (atomicAdd(&cnt[bp], 0u) < 13u) { __builtin_amdgcn_s_sleep(8); }
  }
  __syncthreads();
  __threadfence();                              // acquire before reading peers' Bt

  if (t < 64) { bsL[t] = bs[t]; bnL[t] = bn[t]; gamL[t] = gam[t]; betL[t] = bet[t]; }

  // ================= Phase B: GEMM (A inline from adj) + tail ====================
  f32x4 acc[2][2];
#pragma unroll
  for (int mi = 0; mi < 2; ++mi)
#pragma unroll
    for (int ni = 0; ni < 2; ++ni) acc[mi][ni] = (f32x4){0.f, 0.f, 0.f, 0.f};
  f32x4 accD[2];
  accD[0] = (f32x4){0.f, 0.f, 0.f, 0.f};
  accD[1] = (f32x4){0.f, 0.f, 0.f, 0.f};

  const int sr = t >> 3, sc = t & 7;            // staging row 0..63, chunk 0..7
  int4 aA0, aA1;                                // in-flight adj chunk (8 ints)

  // issue adj loads for K-tile kt (T14 issue-early)
#define A_LOAD(kt_)                                                             \
  {                                                                             \
    int col_ = (kt_) * 64 + sc * 8;                                             \
    int row_ = i0 + sr;                                                         \
    if (row_ < NNODE && col_ < NNODE) {                                         \
      const int4* ap_ = (const int4*)(adj + (size_t)row_ * NNODE + col_);       \
      aA0 = ap_[0]; aA1 = ap_[1];                                               \
    } else {                                                                    \
      aA0.x = 0; aA0.y = 0; aA0.z = 0; aA0.w = 0; aA1 = aA0;                    \
    }                                                                           \
  }
  // convert + swizzled LDS write (T14 write-late)
#define A_WRITE(buf_)                                                           \
  {                                                                             \
    u16* dA_ = lds + (buf_) * BUFU;                                             \
    __align__(16) u16 ob_[8];                                                   \
    ob_[0] = aA0.x ? 0x3F80 : 0; ob_[1] = aA0.y ? 0x3F80 : 0;                   \
    ob_[2] = aA0.z ? 0x3F80 : 0; ob_[3] = aA0.w ? 0x3F80 : 0;                   \
    ob_[4] = aA1.x ? 0x3F80 : 0; ob_[5] = aA1.y ? 0x3F80 : 0;                   \
    ob_[6] = aA1.z ? 0x3F80 : 0; ob_[7] = aA1.w ? 0x3F80 : 0;                   \
    *(uint4*)(dA_ + sr * 64 + ((sc ^ (sr & 7)) * 8)) = *(const uint4*)ob_;      \
  }
  // async B-panel + den staging (pre-swizzled source, linear LDS dest)
#define STAGE_B(kt_, buf_)                                                      \
  {                                                                             \
    int k0_ = (kt_) * 64;                                                       \
    u16* dB_ = lds + (buf_) * BUFU + 4096;                                      \
    _Pragma("unroll")                                                           \
    for (int h_ = 0; h_ < 2; ++h_) {                                            \
      int s_ = h_ * 512 + t; int r_ = s_ >> 3, c_ = s_ & 7;                     \
      gload16(Bt + (size_t)(nb0 + r_) * MP + k0_ + ((c_ ^ (r_ & 7)) * 8),       \
              dB_ + h_ * 4096 + w * 512); }                                     \
    if (w < 2) {                                                                \
      gload16(Bt + (size_t)(nd0 + sr) * MP + k0_ + ((sc ^ (sr & 7)) * 8),       \
              dB_ + 8192 + w * 512); }                                          \
  }

  A_LOAD(0);
  STAGE_B(0, 0);
  A_WRITE(0);
  __syncthreads();

  for (int kt = 0; kt < 13; ++kt) {
    int buf = kt & 1;
    if (kt < 12) { A_LOAD(kt + 1); STAGE_B(kt + 1, buf ^ 1); }
    const u16* As = lds + buf * BUFU;
    const u16* Bs = As + 4096;
#pragma unroll
    for (int kk = 0; kk < 2; ++kk) {
      int q = kk * 4 + g;
      bf16x8 af[2], bfr[2];
#pragma unroll
      for (int mi = 0; mi < 2; ++mi) {
        int ra = wr * 32 + mi * 16 + l15;
        af[mi] = *(const bf16x8*)(As + ra * 64 + ((q ^ (ra & 7)) * 8));
      }
#pragma unroll
      for (int ni = 0; ni < 2; ++ni) {
        int rb = wc * 32 + ni * 16 + l15;
        bfr[ni] = *(const bf16x8*)(Bs + rb * 64 + ((q ^ (rb & 7)) * 8));
      }
#pragma unroll
      for (int mi = 0; mi < 2; ++mi)
#pragma unroll
        for (int ni = 0; ni < 2; ++ni)
          acc[mi][ni] = __builtin_amdgcn_mfma_f32_16x16x32_bf16(af[mi], bfr[ni], acc[mi][ni], 0, 0, 0);
      if (wc == 2 + kk) {                       // den: kk=0 -> wc2, kk=1 -> wc3
        int rd = 128 + l15;
        bf16x8 bd = *(const bf16x8*)(Bs + rd * 64 + ((q ^ (rd & 7)) * 8));
        accD[0] = __builtin_amdgcn_mfma_f32_16x16x32_bf16(af[0], bd, accD[0], 0, 0, 0);
        accD[1] = __builtin_amdgcn_mfma_f32_16x16x32_bf16(af[1], bd, accD[1], 0, 0, 0);
      }
    }
    if (kt < 12) A_WRITE(buf ^ 1);              // write-late: adj latency hidden by MFMA
    __syncthreads();
  }
#undef A_LOAD
#undef A_WRITE
#undef STAGE_B

  // ---- P1: den partial (wc2) -> LDS ; X -> AB2 chunks 0..7 ; W2 reg-staged
  u16* AB2 = lds;                               // [128 rows][128 u16] swizzled
  u16* W2l = lds + 16384;                       // [64 rows][128 u16] swizzled
  if (wc == 2 && l15 < 2) {
#pragma unroll
    for (int mi = 0; mi < 2; ++mi)
#pragma unroll
      for (int j = 0; j < 4; ++j)
        denL[wr * 32 + mi * 16 + g * 4 + j][l15] = accD[mi][j];
  }
#pragma unroll
  for (int q2 = 0; q2 < 2; ++q2) {
    int s = q2 * 512 + t;
    int r = s >> 3, c = s & 7;                  // AB2 row, X-chunk
    int i = i0 + (r & 63);
    int bq = bp * 2 + (r >> 6);
    float4 v0, v1;
    v0.x = v0.y = v0.z = v0.w = 0.f; v1 = v0;
    if (i < NNODE) {
      const float4* xp = (const float4*)(X + ((size_t)bq * NNODE + i) * 64 + c * 8);
      v0 = xp[0]; v1 = xp[1];
    }
    __align__(16) u16 ob[8];
    ob[0] = f2b(v0.x); ob[1] = f2b(v0.y); ob[2] = f2b(v0.z); ob[3] = f2b(v0.w);
    ob[4] = f2b(v1.x); ob[5] = f2b(v1.y); ob[6] = f2b(v1.z); ob[7] = f2b(v1.w);
    *(uint4*)(AB2 + r * 128 + ((c ^ (r & 7)) * 8)) = *(const uint4*)ob;
  }
  {                                             // W2 = [Ws|Wn] bf16, swizzled, from f32
    const float4* wsp = (const float4*)(Ws + sr * 64 + sc * 8);
    const float4* wnp = (const float4*)(Wn + sr * 64 + sc * 8);
    float4 v0 = wsp[0], v1 = wsp[1], v2 = wnp[0], v3 = wnp[1];
    __align__(16) u16 ob[8];
    ob[0] = f2b(v0.x); ob[1] = f2b(v0.y); ob[2] = f2b(v0.z); ob[3] = f2b(v0.w);
    ob[4] = f2b(v1.x); ob[5] = f2b(v1.y); ob[6] = f2b(v1.z); ob[7] = f2b(v1.w);
    *(uint4*)(W2l + sr * 128 + ((sc ^ (sr & 7)) * 8)) = *(const uint4*)ob;
    ob[0] = f2b(v2.x); ob[1] = f2b(v2.y); ob[2] = f2b(v2.z); ob[3] = f2b(v2.w);
    ob[4] = f2b(v3.x); ob[5] = f2b(v3.y); ob[6] = f2b(v3.z); ob[7] = f2b(v3.w);
    *(uint4*)(W2l + sr * 128 + (((sc + 8) ^ (sr & 7)) * 8)) = *(const uint4*)ob;
  }
  __syncthreads();

  // ---- P1b: den partial (wc3) accumulate
  if (wc == 3 && l15 < 2) {
#pragma unroll
    for (int mi = 0; mi < 2; ++mi)
#pragma unroll
      for (int j = 0; j < 4; ++j)
        denL[wr * 32 + mi * 16 + g * 4 + j][l15] += accD[mi][j];
  }
  __syncthreads();

  // ---- P2: Zs = acc/den -> AB2 chunks 8..15
#pragma unroll
  for (int mi = 0; mi < 2; ++mi)
#pragma unroll
    for (int ni = 0; ni < 2; ++ni) {
      int col = wc * 32 + ni * 16 + l15;
      int b2 = col >> 6, f = col & 63;
#pragma unroll
      for (int j = 0; j < 4; ++j) {
        int ri = wr * 32 + mi * 16 + g * 4 + j;
        float d = denL[ri][b2];
        float rd = d > 0.f ? 1.f / d : 0.f;
        int R = b2 * 64 + ri;
        AB2[R * 128 + (((8 + (f >> 3)) ^ (R & 7)) * 8) + (f & 7)] = f2b(acc[mi][ni][j] * rd);
      }
    }
  __syncthreads();

  // ---- P3: second gemm: per batch 64x64, K=128
  const int b2w = w >> 2, mf = w & 3;
  f32x4 a2[4];
#pragma unroll
  for (int nf = 0; nf < 4; ++nf) a2[nf] = (f32x4){0.f, 0.f, 0.f, 0.f};
#pragma unroll
  for (int kk = 0; kk < 4; ++kk) {
    int q2 = kk * 4 + g;
    int ra = b2w * 64 + mf * 16 + l15;
    bf16x8 af = *(const bf16x8*)(AB2 + ra * 128 + ((q2 ^ (ra & 7)) * 8));
#pragma unroll
    for (int nf = 0; nf < 4; ++nf) {
      int rb = nf * 16 + l15;
      bf16x8 bfw = *(const bf16x8*)(W2l + rb * 128 + ((q2 ^ (rb & 7)) * 8));
      a2[nf] = __builtin_amdgcn_mfma_f32_16x16x32_bf16(af, bfw, a2[nf], 0, 0, 0);
    }
  }

  // ---- P4: bias + LN + ReLU + guarded store
#pragma unroll
  for (int j = 0; j < 4; ++j) {
    int ri = mf * 16 + g * 4 + j;
    float d = denL[ri][b2w];
    float bnm = d > 0.f ? 1.f : 0.f;
    float v0 = a2[0][j] + bsL[l15]      + bnm * bnL[l15];
    float v1 = a2[1][j] + bsL[l15 + 16] + bnm * bnL[l15 + 16];
    float v2 = a2[2][j] + bsL[l15 + 32] + bnm * bnL[l15 + 32];
    float v3 = a2[3][j] + bsL[l15 + 48] + bnm * bnL[l15 + 48];
    float s1 = v0 + v1 + v2 + v3;
    float s2 = v0 * v0 + v1 * v1 + v2 * v2 + v3 * v3;
    s1 += __shfl_xor(s1, 1); s2 += __shfl_xor(s2, 1);
    s1 += __shfl_xor(s1, 2); s2 += __shfl_xor(s2, 2);
    s1 += __shfl_xor(s1, 4); s2 += __shfl_xor(s2, 4);
    s1 += __shfl_xor(s1, 8); s2 += __shfl_xor(s2, 8);
    float mu = s1 * (1.f / 64.f);
    float var = fmaxf(s2 * (1.f / 64.f) - mu * mu, 0.f);
    float inv = rsqrtf(var + 1e-5f);
    int node = i0 + ri;
    if (node < NNODE) {
      float* op = out + ((size_t)(bp * 2 + b2w) * NNODE + node) * 64;
      op[l15]      = fmaxf((v0 - mu) * inv * gamL[l15]      + betL[l15],      0.f);
      op[l15 + 16] = fmaxf((v1 - mu) * inv * gamL[l15 + 16] + betL[l15 + 16], 0.f);
      op[l15 + 32] = fmaxf((v2 - mu) * inv * gamL[l15 + 32] + betL[l15 + 32], 0.f);
      op[l15 + 48] = fmaxf((v3 - mu) * inv * gamL[l15 + 48] + betL[l15 + 48], 0.f);
    }
  }
}

extern "C" void kernel_launch(void* const* d_in, const int* in_sizes, int n_in,
                              void* d_out, int out_size, void* d_ws, size_t ws_size,
                              hipStream_t stream) {
  const float* X     = (const float*)d_in[0];
  const int*   adj   = (const int*)d_in[1];
  const float* Wself = (const float*)d_in[2];
  const float* bself = (const float*)d_in[3];
  const float* Wnb   = (const float*)d_in[4];
  const float* bnb   = (const float*)d_in[5];
  // d_in[6] = a_src : cancels in softmax -> unused
  const float* adst  = (const float*)d_in[7];
  // d_in[8] = b_att : cancels in softmax -> unused
  const float* gam   = (const float*)d_in[9];
  const float* bet   = (const float*)d_in[10];
  float* out = (float*)d_out;
  char* ws = (char*)d_ws;

  u16* Bt  = (u16*)(ws);                     // 4224*832 bf16 = 7,028,736 B
  u32* cnt = (u32*)(ws + 7028736);           // 32 group counters = 128 B

  hipMemsetAsync(cnt, 0, 128, stream);
  k_all<<<dim3(416), dim3(512), 0, stream>>>(adj, Wself, Wnb, X, adst,
                                             bself, bnb, gam, bet, Bt, cnt, out);
}

// Round 12
// 29.814 us; speedup vs baseline: 7.0488x; 7.0488x over previous
//
#include <hip/hip_runtime.h>

// GraphConvLayer on MI355X (gfx950). f32 I/O, bf16 inside MFMA.
// softmax_j(src_i+dst_j+b) over neighbors == e_j/sum(e)  (src_i, b cancel).
//   Bt[n][k]: n=b*64+f -> bf16(e_bj * X[b,j,f]) (k=j); n=4096+b -> bf16(e_bj)
//   k_gt: per block (64 nodes x 2 batches): acc = A_tile @ Bt^T, K=832,
//     global_load_lds double-buffer with COUNTED vmcnt + two raw s_barriers per
//     K-step (T4; prefetch stays in flight across barriers). den via extra
//     B-frag (waves wc==2/3 by kk). AB2=[bf16(X)|bf16(acc/den)];
//     out = relu(LN(AB2@W2^T + bias)).
// k_pre: A int32->bf16 0/1 | W2 pre-inverse-swizzled | b1t transpose-scale.

typedef unsigned short u16;
typedef unsigned int u32;
typedef short bf16x8 __attribute__((ext_vector_type(8)));
typedef float f32x4 __attribute__((ext_vector_type(4)));

#define NNODE 784
#define MP 832      // K of big GEMM (padded node count)
#define BUFU 13312  // u16 per dbuf: A 64x64 (4096) + B 128x64 (8192) + den 16x64 (1024)

__device__ __forceinline__ float b2f(u16 h) {
  union { u32 u; float f; } v; v.u = ((u32)h) << 16; return v.f;
}
__device__ __forceinline__ u16 f2b(float f) {
  union { float f; u32 u; } v; v.f = f;
  u32 r = (v.u + 0x7FFFu + ((v.u >> 16) & 1u)) >> 16;
  return (u16)r;
}
__device__ __forceinline__ void gload16(const u16* g, u16* l) {
  __builtin_amdgcn_global_load_lds((const __attribute__((address_space(1))) u32*)g,
                                   (__attribute__((address_space(3))) u32*)l, 16, 0, 0);
}

// ---------- K1: A-convert (bid<364) | W2 build (bid==364) | b1t (bid>=365) ----------
__global__ __launch_bounds__(256) void k_pre(const int* __restrict__ adj,
                                             const float* __restrict__ Ws,
                                             const float* __restrict__ Wn,
                                             const float* __restrict__ X,
                                             const float* __restrict__ adst,
                                             u16* __restrict__ A,
                                             u16* __restrict__ W2,
                                             u16* __restrict__ Bt) {
  const int bid = blockIdx.x;
  const int t = threadIdx.x;
  if (bid < 364) {                            // A: int32 -> bf16 0/1, padded 896x832
    int idx8 = bid * 256 + t;
    int i = idx8 / 104, j8 = idx8 - i * 104;
    __align__(16) u16 o[8];
    if (i < NNODE && j8 < 98) {               // 98*8 = 784
      const int4* ap = (const int4*)(adj + (size_t)i * NNODE + j8 * 8);
      int4 a0 = ap[0], a1 = ap[1];
      o[0] = a0.x ? 0x3F80 : 0; o[1] = a0.y ? 0x3F80 : 0;
      o[2] = a0.z ? 0x3F80 : 0; o[3] = a0.w ? 0x3F80 : 0;
      o[4] = a1.x ? 0x3F80 : 0; o[5] = a1.y ? 0x3F80 : 0;
      o[6] = a1.z ? 0x3F80 : 0; o[7] = a1.w ? 0x3F80 : 0;
    } else {
#pragma unroll
      for (int q = 0; q < 8; ++q) o[q] = 0;
    }
    *(uint4*)(A + (size_t)i * MP + j8 * 8) = *(const uint4*)o;
    return;
  }
  if (bid == 364) {                           // W2: [Ws|Wn] bf16, pre-inverse-swizzled
    int f = t >> 2, cq = t & 3;
#pragma unroll
    for (int q = 0; q < 4; ++q) {
      int c = cq * 4 + q;                     // dest chunk 0..15 (8 u16 each)
      int cs = c ^ (f & 7);                   // source chunk (stays within half)
      const float* src = (cs < 8) ? (Ws + f * 64 + cs * 8) : (Wn + f * 64 + (cs - 8) * 8);
      float4 v0 = ((const float4*)src)[0], v1 = ((const float4*)src)[1];
      __align__(16) u16 ob[8];
      ob[0] = f2b(v0.x); ob[1] = f2b(v0.y); ob[2] = f2b(v0.z); ob[3] = f2b(v0.w);
      ob[4] = f2b(v1.x); ob[5] = f2b(v1.y); ob[6] = f2b(v1.z); ob[7] = f2b(v1.w);
      *(uint4*)(W2 + f * 128 + c * 8) = *(const uint4*)ob;
    }
    return;
  }
  // ---- b1t: fused e + transpose-scale into Bt[4224][832]
  __shared__ float Xs[64][68];
  __shared__ float ad[64];
  __shared__ float es[64];
  int bid2 = bid - 365;
  int b = bid2 / 13, jt = bid2 - b * 13;
  int j0 = jt * 64;
  if (b == 64) {                              // zero pad rows 4160..4223
    int row = 4160 + (t >> 2), c = (t & 3) * 16;
    uint4 z; z.x = 0; z.y = 0; z.z = 0; z.w = 0;
    uint4* p = (uint4*)(Bt + (size_t)row * MP + j0 + c);
    p[0] = z; p[1] = z;
    return;
  }
  int jr = t >> 2, cg = t & 3;
  {
    int j = j0 + jr;
    float4 z4; z4.x = 0.f; z4.y = 0.f; z4.z = 0.f; z4.w = 0.f;
    float4 v0 = z4, v1 = z4, v2 = z4, v3 = z4;
    if (j < NNODE) {
      const float4* xp = (const float4*)(X + ((size_t)b * NNODE + j) * 64 + cg * 16);
      v0 = xp[0]; v1 = xp[1]; v2 = xp[2]; v3 = xp[3];
    }
    float4* d = (float4*)&Xs[jr][cg * 16];
    d[0] = v0; d[1] = v1; d[2] = v2; d[3] = v3;
  }
  if (t < 64) ad[t] = adst[t];
  __syncthreads();
  {
    float dot = 0.f;
#pragma unroll
    for (int q = 0; q < 16; ++q) dot += Xs[jr][cg * 16 + q] * ad[cg * 16 + q];
    dot += __shfl_xor(dot, 1);
    dot += __shfl_xor(dot, 2);
    if (cg == 0) es[jr] = (j0 + jr < NNODE) ? __expf(dot) : 0.f;
  }
  __syncthreads();
  {
    int f = t >> 2, jc = (t & 3) * 16;
    __align__(16) u16 ob[16];
#pragma unroll
    for (int q = 0; q < 16; ++q) ob[q] = f2b(es[jc + q] * Xs[jc + q][f]);
    u16* op = Bt + ((size_t)b * 64 + f) * MP + j0 + jc;
    *(uint4*)op = *(const uint4*)ob;
    *(uint4*)(op + 8) = *(const uint4*)(ob + 8);
  }
  if (t < 64) Bt[(size_t)(4096 + b) * MP + j0 + t] = f2b(es[t]);
}

// ---------- K2: fused GEMM + tail, counted-vmcnt pipelined K-loop ----------
__global__ __launch_bounds__(512, 4) void k_gt(const u16* __restrict__ A,
                                               const u16* __restrict__ Bt,
                                               const u16* __restrict__ W2g,
                                               const float* __restrict__ X,
                                               const float* __restrict__ bs,
                                               const float* __restrict__ bn,
                                               const float* __restrict__ gam,
                                               const float* __restrict__ bet,
                                               float* __restrict__ out) {
  __shared__ __align__(16) u16 lds[2 * BUFU];   // 52 KB dbuf; epilogue union AB2+W2
  __shared__ float denL[64][2];
  __shared__ float bsL[64], bnL[64], gamL[64], betL[64];
  const int t = threadIdx.x;
  const int l = t & 63, w = t >> 6;             // 8 waves
  const int g = l >> 4, l15 = l & 15;
  const int wr = w >> 2, wc = w & 3;            // first gemm: 32x32 per wave

  int wg = (blockIdx.x & 7) * 52 + (blockIdx.x >> 3);   // 416 = 8*52 bijective XCD swizzle
  const int bp = wg / 13;                       // batch pair 0..31 (it-major per XCD)
  const int it = wg - bp * 13;
  const int i0 = it * 64;
  const int nb0 = bp * 128;                     // Bt feat rows
  const int nd0 = 4096 + 2 * bp;                // Bt denom rows

  if (t < 64) { bsL[t] = bs[t]; bnL[t] = bn[t]; gamL[t] = gam[t]; betL[t] = bet[t]; }

  f32x4 acc[2][2];
#pragma unroll
  for (int mi = 0; mi < 2; ++mi)
#pragma unroll
    for (int ni = 0; ni < 2; ++ni) acc[mi][ni] = (f32x4){0.f, 0.f, 0.f, 0.f};
  f32x4 accD[2];
  accD[0] = (f32x4){0.f, 0.f, 0.f, 0.f};
  accD[1] = (f32x4){0.f, 0.f, 0.f, 0.f};

  // per-wave gload_lds issue count: waves 0,1 = 4 (A+2B+den), waves 2..7 = 3
#define STAGE(kt_, buf_)                                                          \
  {                                                                               \
    int k0_ = (kt_) * 64;                                                         \
    u16* dA_ = lds + (buf_) * BUFU;                                               \
    u16* dB_ = dA_ + 4096;                                                        \
    { int r_ = t >> 3, c_ = t & 7;                                                \
      gload16(A + (size_t)(i0 + r_) * MP + k0_ + ((c_ ^ (r_ & 7)) * 8),           \
              dA_ + w * 512); }                                                   \
    _Pragma("unroll")                                                             \
    for (int h_ = 0; h_ < 2; ++h_) {                                              \
      int s_ = h_ * 512 + t; int r_ = s_ >> 3, c_ = s_ & 7;                       \
      gload16(Bt + (size_t)(nb0 + r_) * MP + k0_ + ((c_ ^ (r_ & 7)) * 8),         \
              dB_ + h_ * 4096 + w * 512); }                                       \
    if (w < 2) { int r_ = t >> 3, c_ = t & 7;                                     \
      gload16(Bt + (size_t)(nd0 + r_) * MP + k0_ + ((c_ ^ (r_ & 7)) * 8),         \
              dB_ + 8192 + w * 512); }                                            \
  }

  STAGE(0, 0);                                  // prologue; drained at kt=0's wait

  for (int kt = 0; kt < 13; ++kt) {
    int buf = kt & 1;
    if (kt < 12) {
      STAGE(kt + 1, buf ^ 1);                   // stays in flight across barriers
      if (w < 2) asm volatile("s_waitcnt vmcnt(4)" ::: "memory");
      else       asm volatile("s_waitcnt vmcnt(3)" ::: "memory");
    } else {
      asm volatile("s_waitcnt vmcnt(0)" ::: "memory");
    }
    __builtin_amdgcn_s_barrier();               // all waves' STAGE(kt) data ready
    __builtin_amdgcn_sched_barrier(0);
    const u16* As = lds + buf * BUFU;
    const u16* Bs = As + 4096;
#pragma unroll
    for (int kk = 0; kk < 2; ++kk) {
      int q = kk * 4 + g;
      bf16x8 af[2], bfr[2];
#pragma unroll
      for (int mi = 0; mi < 2; ++mi) {
        int ra = wr * 32 + mi * 16 + l15;
        af[mi] = *(const bf16x8*)(As + ra * 64 + ((q ^ (ra & 7)) * 8));
      }
#pragma unroll
      for (int ni = 0; ni < 2; ++ni) {
        int rb = wc * 32 + ni * 16 + l15;
        bfr[ni] = *(const bf16x8*)(Bs + rb * 64 + ((q ^ (rb & 7)) * 8));
      }
#pragma unroll
      for (int mi = 0; mi < 2; ++mi)
#pragma unroll
        for (int ni = 0; ni < 2; ++ni)
          acc[mi][ni] = __builtin_amdgcn_mfma_f32_16x16x32_bf16(af[mi], bfr[ni], acc[mi][ni], 0, 0, 0);
      if (wc == 2 + kk) {                       // den: kk=0 -> wc2, kk=1 -> wc3
        int rd = 128 + l15;
        bf16x8 bd = *(const bf16x8*)(Bs + rd * 64 + ((q ^ (rd & 7)) * 8));
        accD[0] = __builtin_amdgcn_mfma_f32_16x16x32_bf16(af[0], bd, accD[0], 0, 0, 0);
        accD[1] = __builtin_amdgcn_mfma_f32_16x16x32_bf16(af[1], bd, accD[1], 0, 0, 0);
      }
    }
    __builtin_amdgcn_sched_barrier(0);
    __builtin_amdgcn_s_barrier();               // all reads of buf done (next kt+1 writes it)
  }
#undef STAGE

  // ---- P1: den partial (wc2) -> LDS ; X -> AB2 chunks 0..7 ; W2 -> LDS
  u16* AB2 = lds;                               // [128 rows][128 u16] swizzled
  u16* W2l = lds + 16384;                       // [64 rows][128 u16] swizzled
  if (wc == 2 && l15 < 2) {
#pragma unroll
    for (int mi = 0; mi < 2; ++mi)
#pragma unroll
      for (int j = 0; j < 4; ++j)
        denL[wr * 32 + mi * 16 + g * 4 + j][l15] = accD[mi][j];
  }
#pragma unroll
  for (int q2 = 0; q2 < 2; ++q2) {
    int s = q2 * 512 + t;
    int r = s >> 3, c = s & 7;                  // AB2 row, X-chunk
    int i = i0 + (r & 63);
    int bq = bp * 2 + (r >> 6);
    float4 v0, v1;
    v0.x = v0.y = v0.z = v0.w = 0.f; v1 = v0;
    if (i < NNODE) {
      const float4* xp = (const float4*)(X + ((size_t)bq * NNODE + i) * 64 + c * 8);
      v0 = xp[0]; v1 = xp[1];
    }
    __align__(16) u16 ob[8];
    ob[0] = f2b(v0.x); ob[1] = f2b(v0.y); ob[2] = f2b(v0.z); ob[3] = f2b(v0.w);
    ob[4] = f2b(v1.x); ob[5] = f2b(v1.y); ob[6] = f2b(v1.z); ob[7] = f2b(v1.w);
    *(uint4*)(AB2 + r * 128 + ((c ^ (r & 7)) * 8)) = *(const uint4*)ob;
  }
#pragma unroll
  for (int q2 = 0; q2 < 2; ++q2)
    gload16(W2g + q2 * 4096 + w * 512 + l * 8, W2l + q2 * 4096 + w * 512);
  __syncthreads();                              // full drain (once) — W2l + AB2 ready

  // ---- P1b: den partial (wc3) accumulate
  if (wc == 3 && l15 < 2) {
#pragma unroll
    for (int mi = 0; mi < 2; ++mi)
#pragma unroll
      for (int j = 0; j < 4; ++j)
        denL[wr * 32 + mi * 16 + g * 4 + j][l15] += accD[mi][j];
  }
  __syncthreads();

  // ---- P2: Zs = acc/den -> AB2 chunks 8..15
#pragma unroll
  for (int mi = 0; mi < 2; ++mi)
#pragma unroll
    for (int ni = 0; ni < 2; ++ni) {
      int col = wc * 32 + ni * 16 + l15;
      int b2 = col >> 6, f = col & 63;
#pragma unroll
      for (int j = 0; j < 4; ++j) {
        int ri = wr * 32 + mi * 16 + g * 4 + j;
        float d = denL[ri][b2];
        float rd = d > 0.f ? 1.f / d : 0.f;
        int R = b2 * 64 + ri;
        AB2[R * 128 + (((8 + (f >> 3)) ^ (R & 7)) * 8) + (f & 7)] = f2b(acc[mi][ni][j] * rd);
      }
    }
  __syncthreads();

  // ---- P3: second gemm: per batch 64x64, K=128
  const int b2w = w >> 2, mf = w & 3;
  f32x4 a2[4];
#pragma unroll
  for (int nf = 0; nf < 4; ++nf) a2[nf] = (f32x4){0.f, 0.f, 0.f, 0.f};
#pragma unroll
  for (int kk = 0; kk < 4; ++kk) {
    int q2 = kk * 4 + g;
    int ra = b2w * 64 + mf * 16 + l15;
    bf16x8 af = *(const bf16x8*)(AB2 + ra * 128 + ((q2 ^ (ra & 7)) * 8));
#pragma unroll
    for (int nf = 0; nf < 4; ++nf) {
      int rb = nf * 16 + l15;
      bf16x8 bfw = *(const bf16x8*)(W2l + rb * 128 + ((q2 ^ (rb & 7)) * 8));
      a2[nf] = __builtin_amdgcn_mfma_f32_16x16x32_bf16(af, bfw, a2[nf], 0, 0, 0);
    }
  }

  // ---- P4: bias + LN + ReLU + guarded store
#pragma unroll
  for (int j = 0; j < 4; ++j) {
    int ri = mf * 16 + g * 4 + j;
    float d = denL[ri][b2w];
    float bnm = d > 0.f ? 1.f : 0.f;
    float v0 = a2[0][j] + bsL[l15]      + bnm * bnL[l15];
    float v1 = a2[1][j] + bsL[l15 + 16] + bnm * bnL[l15 + 16];
    float v2 = a2[2][j] + bsL[l15 + 32] + bnm * bnL[l15 + 32];
    float v3 = a2[3][j] + bsL[l15 + 48] + bnm * bnL[l15 + 48];
    float s1 = v0 + v1 + v2 + v3;
    float s2 = v0 * v0 + v1 * v1 + v2 * v2 + v3 * v3;
    s1 += __shfl_xor(s1, 1); s2 += __shfl_xor(s2, 1);
    s1 += __shfl_xor(s1, 2); s2 += __shfl_xor(s2, 2);
    s1 += __shfl_xor(s1, 4); s2 += __shfl_xor(s2, 4);
    s1 += __shfl_xor(s1, 8); s2 += __shfl_xor(s2, 8);
    float mu = s1 * (1.f / 64.f);
    float var = fmaxf(s2 * (1.f / 64.f) - mu * mu, 0.f);
    float inv = rsqrtf(var + 1e-5f);
    int node = i0 + ri;
    if (node < NNODE) {
      float* op = out + ((size_t)(bp * 2 + b2w) * NNODE + node) * 64;
      op[l15]      = fmaxf((v0 - mu) * inv * gamL[l15]      + betL[l15],      0.f);
      op[l15 + 16] = fmaxf((v1 - mu) * inv * gamL[l15 + 16] + betL[l15 + 16], 0.f);
      op[l15 + 32] = fmaxf((v2 - mu) * inv * gamL[l15 + 32] + betL[l15 + 32], 0.f);
      op[l15 + 48] = fmaxf((v3 - mu) * inv * gamL[l15 + 48] + betL[l15 + 48], 0.f);
    }
  }
}

extern "C" void kernel_launch(void* const* d_in, const int* in_sizes, int n_in,
                              void* d_out, int out_size, void* d_ws, size_t ws_size,
                              hipStream_t stream) {
  const float* X     = (const float*)d_in[0];
  const int*   adj   = (const int*)d_in[1];
  const float* Wself = (const float*)d_in[2];
  const float* bself = (const float*)d_in[3];
  const float* Wnb   = (const float*)d_in[4];
  const float* bnb   = (const float*)d_in[5];
  // d_in[6] = a_src : cancels in softmax -> unused
  const float* adst  = (const float*)d_in[7];
  // d_in[8] = b_att : cancels in softmax -> unused
  const float* gam   = (const float*)d_in[9];
  const float* bet   = (const float*)d_in[10];
  float* out = (float*)d_out;
  char* ws = (char*)d_ws;

  u16* Apad = (u16*)(ws);                    // 896*832  bf16 = 1,490,944 B
  u16* W2g  = (u16*)(ws + 1490944);          // 64*128   bf16 =    16,384 B
  u16* Bt   = (u16*)(ws + 1507328);          // 4224*832 bf16 = 7,028,736 B (end 8,536,064)

  k_pre<<<dim3(1210), dim3(256), 0, stream>>>(adj, Wself, Wnb, X, adst, Apad, W2g, Bt);
  k_gt <<<dim3(416),  dim3(512), 0, stream>>>(Apad, Bt, W2g, X, bself, bnb, gam, bet, out);
}

// Round 13
// 28.474 us; speedup vs baseline: 7.3806x; 1.0471x over previous
//
#include <hip/hip_runtime.h>

// GraphConvLayer on MI355X (gfx950). f32 I/O, bf16 inside MFMA.
// softmax_j(src_i+dst_j+b) over neighbors == e_j/sum(e)  (src_i, b cancel).
//   Bt[n][k]: n=b*64+f -> bf16(e_bj * X[b,j,f]) (k=j); n=4096+b -> bf16(e_bj)
//   k_gt: per block (64 nodes x 2 batches): acc = A_tile @ Bt^T, K=832,
//     global_load_lds double-buffer with COUNTED vmcnt + two raw s_barriers per
//     K-step. den via extra B-frag (waves wc==2/3 by kk).
//     AB2=[bf16(X)|bf16(acc/den)]; out = relu(LN(AB2@W2^T + bias)).
//   LDS trimmed to exactly 53,248 B (pure dbuf; denL overlaid in dead dbuf tail,
//   biases read from global in P4) -> 3 blocks/CU (24 waves/CU) for stall-filling.
// k_pre: A int32->bf16 0/1 | W2 pre-inverse-swizzled | b1t transpose-scale.

typedef unsigned short u16;
typedef unsigned int u32;
typedef short bf16x8 __attribute__((ext_vector_type(8)));
typedef float f32x4 __attribute__((ext_vector_type(4)));

#define NNODE 784
#define MP 832      // K of big GEMM (padded node count)
#define BUFU 13312  // u16 per dbuf: A 64x64 (4096) + B 128x64 (8192) + den 16x64 (1024)

__device__ __forceinline__ float b2f(u16 h) {
  union { u32 u; float f; } v; v.u = ((u32)h) << 16; return v.f;
}
__device__ __forceinline__ u16 f2b(float f) {
  union { float f; u32 u; } v; v.f = f;
  u32 r = (v.u + 0x7FFFu + ((v.u >> 16) & 1u)) >> 16;
  return (u16)r;
}
__device__ __forceinline__ void gload16(const u16* g, u16* l) {
  __builtin_amdgcn_global_load_lds((const __attribute__((address_space(1))) u32*)g,
                                   (__attribute__((address_space(3))) u32*)l, 16, 0, 0);
}

// ---------- K1: A-convert (bid<364) | W2 build (bid==364) | b1t (bid>=365) ----------
__global__ __launch_bounds__(256) void k_pre(const int* __restrict__ adj,
                                             const float* __restrict__ Ws,
                                             const float* __restrict__ Wn,
                                             const float* __restrict__ X,
                                             const float* __restrict__ adst,
                                             u16* __restrict__ A,
                                             u16* __restrict__ W2,
                                             u16* __restrict__ Bt) {
  const int bid = blockIdx.x;
  const int t = threadIdx.x;
  if (bid < 364) {                            // A: int32 -> bf16 0/1, padded 896x832
    int idx8 = bid * 256 + t;
    int i = idx8 / 104, j8 = idx8 - i * 104;
    __align__(16) u16 o[8];
    if (i < NNODE && j8 < 98) {               // 98*8 = 784
      const int4* ap = (const int4*)(adj + (size_t)i * NNODE + j8 * 8);
      int4 a0 = ap[0], a1 = ap[1];
      o[0] = a0.x ? 0x3F80 : 0; o[1] = a0.y ? 0x3F80 : 0;
      o[2] = a0.z ? 0x3F80 : 0; o[3] = a0.w ? 0x3F80 : 0;
      o[4] = a1.x ? 0x3F80 : 0; o[5] = a1.y ? 0x3F80 : 0;
      o[6] = a1.z ? 0x3F80 : 0; o[7] = a1.w ? 0x3F80 : 0;
    } else {
#pragma unroll
      for (int q = 0; q < 8; ++q) o[q] = 0;
    }
    *(uint4*)(A + (size_t)i * MP + j8 * 8) = *(const uint4*)o;
    return;
  }
  if (bid == 364) {                           // W2: [Ws|Wn] bf16, pre-inverse-swizzled
    int f = t >> 2, cq = t & 3;
#pragma unroll
    for (int q = 0; q < 4; ++q) {
      int c = cq * 4 + q;                     // dest chunk 0..15 (8 u16 each)
      int cs = c ^ (f & 7);                   // source chunk (stays within half)
      const float* src = (cs < 8) ? (Ws + f * 64 + cs * 8) : (Wn + f * 64 + (cs - 8) * 8);
      float4 v0 = ((const float4*)src)[0], v1 = ((const float4*)src)[1];
      __align__(16) u16 ob[8];
      ob[0] = f2b(v0.x); ob[1] = f2b(v0.y); ob[2] = f2b(v0.z); ob[3] = f2b(v0.w);
      ob[4] = f2b(v1.x); ob[5] = f2b(v1.y); ob[6] = f2b(v1.z); ob[7] = f2b(v1.w);
      *(uint4*)(W2 + f * 128 + c * 8) = *(const uint4*)ob;
    }
    return;
  }
  // ---- b1t: fused e + transpose-scale into Bt[4224][832]
  __shared__ float Xs[64][68];
  __shared__ float ad[64];
  __shared__ float es[64];
  int bid2 = bid - 365;
  int b = bid2 / 13, jt = bid2 - b * 13;
  int j0 = jt * 64;
  if (b == 64) {                              // zero pad rows 4160..4223
    int row = 4160 + (t >> 2), c = (t & 3) * 16;
    uint4 z; z.x = 0; z.y = 0; z.z = 0; z.w = 0;
    uint4* p = (uint4*)(Bt + (size_t)row * MP + j0 + c);
    p[0] = z; p[1] = z;
    return;
  }
  int jr = t >> 2, cg = t & 3;
  {
    int j = j0 + jr;
    float4 z4; z4.x = 0.f; z4.y = 0.f; z4.z = 0.f; z4.w = 0.f;
    float4 v0 = z4, v1 = z4, v2 = z4, v3 = z4;
    if (j < NNODE) {
      const float4* xp = (const float4*)(X + ((size_t)b * NNODE + j) * 64 + cg * 16);
      v0 = xp[0]; v1 = xp[1]; v2 = xp[2]; v3 = xp[3];
    }
    float4* d = (float4*)&Xs[jr][cg * 16];
    d[0] = v0; d[1] = v1; d[2] = v2; d[3] = v3;
  }
  if (t < 64) ad[t] = adst[t];
  __syncthreads();
  {
    float dot = 0.f;
#pragma unroll
    for (int q = 0; q < 16; ++q) dot += Xs[jr][cg * 16 + q] * ad[cg * 16 + q];
    dot += __shfl_xor(dot, 1);
    dot += __shfl_xor(dot, 2);
    if (cg == 0) es[jr] = (j0 + jr < NNODE) ? __expf(dot) : 0.f;
  }
  __syncthreads();
  {
    int f = t >> 2, jc = (t & 3) * 16;
    __align__(16) u16 ob[16];
#pragma unroll
    for (int q = 0; q < 16; ++q) ob[q] = f2b(es[jc + q] * Xs[jc + q][f]);
    u16* op = Bt + ((size_t)b * 64 + f) * MP + j0 + jc;
    *(uint4*)op = *(const uint4*)ob;
    *(uint4*)(op + 8) = *(const uint4*)(ob + 8);
  }
  if (t < 64) Bt[(size_t)(4096 + b) * MP + j0 + t] = f2b(es[t]);
}

// ---------- K2: fused GEMM + tail, counted-vmcnt K-loop, 3 blocks/CU ----------
__global__ __launch_bounds__(512, 6) void k_gt(const u16* __restrict__ A,
                                               const u16* __restrict__ Bt,
                                               const u16* __restrict__ W2g,
                                               const float* __restrict__ X,
                                               const float* __restrict__ bs,
                                               const float* __restrict__ bn,
                                               const float* __restrict__ gam,
                                               const float* __restrict__ bet,
                                               float* __restrict__ out) {
  __shared__ __align__(16) u16 lds[2 * BUFU];   // 53,248 B total — ONLY shared alloc
  const int t = threadIdx.x;
  const int l = t & 63, w = t >> 6;             // 8 waves
  const int g = l >> 4, l15 = l & 15;
  const int wr = w >> 2, wc = w & 3;            // first gemm: 32x32 per wave

  int wg = (blockIdx.x & 7) * 52 + (blockIdx.x >> 3);   // 416 = 8*52 bijective XCD swizzle
  const int bp = wg / 13;                       // batch pair 0..31 (it-major per XCD)
  const int it = wg - bp * 13;
  const int i0 = it * 64;
  const int nb0 = bp * 128;                     // Bt feat rows
  const int nd0 = 4096 + 2 * bp;                // Bt denom rows

  f32x4 acc[2][2];
#pragma unroll
  for (int mi = 0; mi < 2; ++mi)
#pragma unroll
    for (int ni = 0; ni < 2; ++ni) acc[mi][ni] = (f32x4){0.f, 0.f, 0.f, 0.f};
  f32x4 accD[2];
  accD[0] = (f32x4){0.f, 0.f, 0.f, 0.f};
  accD[1] = (f32x4){0.f, 0.f, 0.f, 0.f};

  // per-wave gload_lds issue count: waves 0,1 = 4 (A+2B+den), waves 2..7 = 3
#define STAGE(kt_, buf_)                                                          \
  {                                                                               \
    int k0_ = (kt_) * 64;                                                         \
    u16* dA_ = lds + (buf_) * BUFU;                                               \
    u16* dB_ = dA_ + 4096;                                                        \
    { int r_ = t >> 3, c_ = t & 7;                                                \
      gload16(A + (size_t)(i0 + r_) * MP + k0_ + ((c_ ^ (r_ & 7)) * 8),           \
              dA_ + w * 512); }                                                   \
    _Pragma("unroll")                                                             \
    for (int h_ = 0; h_ < 2; ++h_) {                                              \
      int s_ = h_ * 512 + t; int r_ = s_ >> 3, c_ = s_ & 7;                       \
      gload16(Bt + (size_t)(nb0 + r_) * MP + k0_ + ((c_ ^ (r_ & 7)) * 8),         \
              dB_ + h_ * 4096 + w * 512); }                                       \
    if (w < 2) { int r_ = t >> 3, c_ = t & 7;                                     \
      gload16(Bt + (size_t)(nd0 + r_) * MP + k0_ + ((c_ ^ (r_ & 7)) * 8),         \
              dB_ + 8192 + w * 512); }                                            \
  }

  STAGE(0, 0);                                  // prologue; drained at kt=0's wait

  for (int kt = 0; kt < 13; ++kt) {
    int buf = kt & 1;
    if (kt < 12) {
      STAGE(kt + 1, buf ^ 1);                   // stays in flight across barriers
      if (w < 2) asm volatile("s_waitcnt vmcnt(4)" ::: "memory");
      else       asm volatile("s_waitcnt vmcnt(3)" ::: "memory");
    } else {
      asm volatile("s_waitcnt vmcnt(0)" ::: "memory");
    }
    __builtin_amdgcn_s_barrier();               // all waves' STAGE(kt) data ready
    __builtin_amdgcn_sched_barrier(0);
    const u16* As = lds + buf * BUFU;
    const u16* Bs = As + 4096;
#pragma unroll
    for (int kk = 0; kk < 2; ++kk) {
      int q = kk * 4 + g;
      bf16x8 af[2], bfr[2];
#pragma unroll
      for (int mi = 0; mi < 2; ++mi) {
        int ra = wr * 32 + mi * 16 + l15;
        af[mi] = *(const bf16x8*)(As + ra * 64 + ((q ^ (ra & 7)) * 8));
      }
#pragma unroll
      for (int ni = 0; ni < 2; ++ni) {
        int rb = wc * 32 + ni * 16 + l15;
        bfr[ni] = *(const bf16x8*)(Bs + rb * 64 + ((q ^ (rb & 7)) * 8));
      }
#pragma unroll
      for (int mi = 0; mi < 2; ++mi)
#pragma unroll
        for (int ni = 0; ni < 2; ++ni)
          acc[mi][ni] = __builtin_amdgcn_mfma_f32_16x16x32_bf16(af[mi], bfr[ni], acc[mi][ni], 0, 0, 0);
      if (wc == 2 + kk) {                       // den: kk=0 -> wc2, kk=1 -> wc3
        int rd = 128 + l15;
        bf16x8 bd = *(const bf16x8*)(Bs + rd * 64 + ((q ^ (rd & 7)) * 8));
        accD[0] = __builtin_amdgcn_mfma_f32_16x16x32_bf16(af[0], bd, accD[0], 0, 0, 0);
        accD[1] = __builtin_amdgcn_mfma_f32_16x16x32_bf16(af[1], bd, accD[1], 0, 0, 0);
      }
    }
    __builtin_amdgcn_sched_barrier(0);
    __builtin_amdgcn_s_barrier();               // all reads of buf done (next kt+1 writes it)
  }
#undef STAGE

  // ---- Epilogue LDS overlay: AB2 [0,32768)B ; W2l [32768,49152)B ; denL [49152,49664)B
  u16* AB2 = lds;                               // [128 rows][128 u16] swizzled
  u16* W2l = lds + 16384;                       // [64 rows][128 u16] swizzled
  float (*denL)[2] = (float (*)[2])((char*)lds + 49152);   // [64][2]

  // ---- P1: den partial (wc2) -> LDS ; X -> AB2 chunks 0..7 ; W2 -> LDS
  if (wc == 2 && l15 < 2) {
#pragma unroll
    for (int mi = 0; mi < 2; ++mi)
#pragma unroll
      for (int j = 0; j < 4; ++j)
        denL[wr * 32 + mi * 16 + g * 4 + j][l15] = accD[mi][j];
  }
#pragma unroll
  for (int q2 = 0; q2 < 2; ++q2) {
    int s = q2 * 512 + t;
    int r = s >> 3, c = s & 7;                  // AB2 row, X-chunk
    int i = i0 + (r & 63);
    int bq = bp * 2 + (r >> 6);
    float4 v0, v1;
    v0.x = v0.y = v0.z = v0.w = 0.f; v1 = v0;
    if (i < NNODE) {
      const float4* xp = (const float4*)(X + ((size_t)bq * NNODE + i) * 64 + c * 8);
      v0 = xp[0]; v1 = xp[1];
    }
    __align__(16) u16 ob[8];
    ob[0] = f2b(v0.x); ob[1] = f2b(v0.y); ob[2] = f2b(v0.z); ob[3] = f2b(v0.w);
    ob[4] = f2b(v1.x); ob[5] = f2b(v1.y); ob[6] = f2b(v1.z); ob[7] = f2b(v1.w);
    *(uint4*)(AB2 + r * 128 + ((c ^ (r & 7)) * 8)) = *(const uint4*)ob;
  }
#pragma unroll
  for (int q2 = 0; q2 < 2; ++q2)
    gload16(W2g + q2 * 4096 + w * 512 + l * 8, W2l + q2 * 4096 + w * 512);
  __syncthreads();                              // full drain (once) — W2l + AB2 ready

  // ---- P1b: den partial (wc3) accumulate
  if (wc == 3 && l15 < 2) {
#pragma unroll
    for (int mi = 0; mi < 2; ++mi)
#pragma unroll
      for (int j = 0; j < 4; ++j)
        denL[wr * 32 + mi * 16 + g * 4 + j][l15] += accD[mi][j];
  }
  __syncthreads();

  // ---- P2: Zs = acc/den -> AB2 chunks 8..15
#pragma unroll
  for (int mi = 0; mi < 2; ++mi)
#pragma unroll
    for (int ni = 0; ni < 2; ++ni) {
      int col = wc * 32 + ni * 16 + l15;
      int b2 = col >> 6, f = col & 63;
#pragma unroll
      for (int j = 0; j < 4; ++j) {
        int ri = wr * 32 + mi * 16 + g * 4 + j;
        float d = denL[ri][b2];
        float rd = d > 0.f ? 1.f / d : 0.f;
        int R = b2 * 64 + ri;
        AB2[R * 128 + (((8 + (f >> 3)) ^ (R & 7)) * 8) + (f & 7)] = f2b(acc[mi][ni][j] * rd);
      }
    }
  __syncthreads();

  // ---- P3: second gemm: per batch 64x64, K=128
  const int b2w = w >> 2, mf = w & 3;
  f32x4 a2[4];
#pragma unroll
  for (int nf = 0; nf < 4; ++nf) a2[nf] = (f32x4){0.f, 0.f, 0.f, 0.f};
#pragma unroll
  for (int kk = 0; kk < 4; ++kk) {
    int q2 = kk * 4 + g;
    int ra = b2w * 64 + mf * 16 + l15;
    bf16x8 af = *(const bf16x8*)(AB2 + ra * 128 + ((q2 ^ (ra & 7)) * 8));
#pragma unroll
    for (int nf = 0; nf < 4; ++nf) {
      int rb = nf * 16 + l15;
      bf16x8 bfw = *(const bf16x8*)(W2l + rb * 128 + ((q2 ^ (rb & 7)) * 8));
      a2[nf] = __builtin_amdgcn_mfma_f32_16x16x32_bf16(af, bfw, a2[nf], 0, 0, 0);
    }
  }

  // ---- P4: bias + LN + ReLU + guarded store (biases straight from global, L2-hot)
  const float bs0 = bs[l15],      bn0 = bn[l15],      ga0 = gam[l15],      be0 = bet[l15];
  const float bs1 = bs[l15 + 16], bn1 = bn[l15 + 16], ga1 = gam[l15 + 16], be1 = bet[l15 + 16];
  const float bs2 = bs[l15 + 32], bn2 = bn[l15 + 32], ga2 = gam[l15 + 32], be2 = bet[l15 + 32];
  const float bs3 = bs[l15 + 48], bn3 = bn[l15 + 48], ga3 = gam[l15 + 48], be3 = bet[l15 + 48];
#pragma unroll
  for (int j = 0; j < 4; ++j) {
    int ri = mf * 16 + g * 4 + j;
    float d = denL[ri][b2w];
    float bnm = d > 0.f ? 1.f : 0.f;
    float v0 = a2[0][j] + bs0 + bnm * bn0;
    float v1 = a2[1][j] + bs1 + bnm * bn1;
    float v2 = a2[2][j] + bs2 + bnm * bn2;
    float v3 = a2[3][j] + bs3 + bnm * bn3;
    float s1 = v0 + v1 + v2 + v3;
    float s2 = v0 * v0 + v1 * v1 + v2 * v2 + v3 * v3;
    s1 += __shfl_xor(s1, 1); s2 += __shfl_xor(s2, 1);
    s1 += __shfl_xor(s1, 2); s2 += __shfl_xor(s2, 2);
    s1 += __shfl_xor(s1, 4); s2 += __shfl_xor(s2, 4);
    s1 += __shfl_xor(s1, 8); s2 += __shfl_xor(s2, 8);
    float mu = s1 * (1.f / 64.f);
    float var = fmaxf(s2 * (1.f / 64.f) - mu * mu, 0.f);
    float inv = rsqrtf(var + 1e-5f);
    int node = i0 + ri;
    if (node < NNODE) {
      float* op = out + ((size_t)(bp * 2 + b2w) * NNODE + node) * 64;
      op[l15]      = fmaxf((v0 - mu) * inv * ga0 + be0, 0.f);
      op[l15 + 16] = fmaxf((v1 - mu) * inv * ga1 + be1, 0.f);
      op[l15 + 32] = fmaxf((v2 - mu) * inv * ga2 + be2, 0.f);
      op[l15 + 48] = fmaxf((v3 - mu) * inv * ga3 + be3, 0.f);
    }
  }
}

extern "C" void kernel_launch(void* const* d_in, const int* in_sizes, int n_in,
                              void* d_out, int out_size, void* d_ws, size_t ws_size,
                              hipStream_t stream) {
  const float* X     = (const float*)d_in[0];
  const int*   adj   = (const int*)d_in[1];
  const float* Wself = (const float*)d_in[2];
  const float* bself = (const float*)d_in[3];
  const float* Wnb   = (const float*)d_in[4];
  const float* bnb   = (const float*)d_in[5];
  // d_in[6] = a_src : cancels in softmax -> unused
  const float* adst  = (const float*)d_in[7];
  // d_in[8] = b_att : cancels in softmax -> unused
  const float* gam   = (const float*)d_in[9];
  const float* bet   = (const float*)d_in[10];
  float* out = (float*)d_out;
  char* ws = (char*)d_ws;

  u16* Apad = (u16*)(ws);                    // 896*832  bf16 = 1,490,944 B
  u16* W2g  = (u16*)(ws + 1490944);          // 64*128   bf16 =    16,384 B
  u16* Bt   = (u16*)(ws + 1507328);          // 4224*832 bf16 = 7,028,736 B (end 8,536,064)

  k_pre<<<dim3(1210), dim3(256), 0, stream>>>(adj, Wself, Wnb, X, adst, Apad, W2g, Bt);
  k_gt <<<dim3(416),  dim3(512), 0, stream>>>(Apad, Bt, W2g, X, bself, bnb, gam, bet, out);
}